// Round 1
// baseline (143.108 us; speedup 1.0000x reference)
//
#include <hip/hip_runtime.h>

// RESCAL scoring: out[b] = e_h^T W_r e_t
// E: [1e6, 128] f32 (row L2-normalized), W: [1000, 128, 128] f32,
// heads/rels/tails: [16384] i32, out: [16384] f32.
//
// Baseline structure: one 64-lane wave per batch element.
//   lane l owns output columns {2l, 2l+1}; W read as float2 -> each loop
//   iteration is one fully-coalesced 512B wave read of W row d.
//   e_h staged in per-wave LDS slice for scalar broadcast (bank-broadcast,
//   conflict-free). Final score = wave shuffle-reduce of mid . e_t.

#define RANK 128

__global__ __launch_bounds__(256) void rescal_score(
    const float* __restrict__ E, const float* __restrict__ W,
    const int* __restrict__ heads, const int* __restrict__ rels,
    const int* __restrict__ tails, float* __restrict__ out, int batch)
{
  const int wib  = threadIdx.x >> 6;   // wave index in block, 0..3
  const int lane = threadIdx.x & 63;
  const int b    = blockIdx.x * 4 + wib;

  __shared__ float eh_s[4][RANK];

  // Uniform control flow: clamp indices for tail waves, mask the store.
  const bool valid = (b < batch);
  const int bb = valid ? b : 0;
  const int h = heads[bb];
  const int r = rels[bb];
  const int t = tails[bb];

  const float2* eh2 = (const float2*)(E + (long long)h * RANK);
  const float2* et2 = (const float2*)(E + (long long)t * RANK);
  const float2* W2  = (const float2*)(W + (long long)r * RANK * RANK);

  // Stage e_h into this wave's LDS slice (2 floats per lane = 128).
  float2 ehv = eh2[lane];
  eh_s[wib][2 * lane]     = ehv.x;
  eh_s[wib][2 * lane + 1] = ehv.y;
  __syncthreads();

  // mid[k] = sum_d e_h[d] * W_r[d][k]; lane holds k = 2*lane, 2*lane+1.
  float mx = 0.f, my = 0.f;
  #pragma unroll 8
  for (int d = 0; d < RANK; ++d) {
    const float   x = eh_s[wib][d];        // LDS broadcast (same addr all lanes)
    const float2  w = W2[d * 64 + lane];   // coalesced: 64 lanes x 8B contiguous
    mx = fmaf(x, w.x, mx);
    my = fmaf(x, w.y, my);
  }

  // score = mid . e_t, then reduce across the wave.
  const float2 etv = et2[lane];
  float s = fmaf(mx, etv.x, my * etv.y);
  #pragma unroll
  for (int off = 32; off > 0; off >>= 1)
    s += __shfl_down(s, off, 64);

  if (valid && lane == 0) out[b] = s;
}

extern "C" void kernel_launch(void* const* d_in, const int* in_sizes, int n_in,
                              void* d_out, int out_size, void* d_ws, size_t ws_size,
                              hipStream_t stream)
{
  const float* E     = (const float*)d_in[0];
  const float* W     = (const float*)d_in[1];
  const int*   heads = (const int*)d_in[2];
  const int*   rels  = (const int*)d_in[3];
  const int*   tails = (const int*)d_in[4];
  float* out = (float*)d_out;

  const int batch  = in_sizes[2];            // 16384
  const int blocks = (batch + 3) / 4;        // 4 waves (batch elems) per block
  rescal_score<<<blocks, 256, 0, stream>>>(E, W, heads, rels, tails, out, batch);
}

// Round 2
// 53.279 us; speedup vs baseline: 2.6860x; 2.6860x over previous
//
#include <hip/hip_runtime.h>

// RESCAL scoring: out[b] = e_h^T W_r e_t
// Round 2: sort batch by relation, then register-resident W_r slices.
//   Aux kernels: zero-hist -> histogram -> prefix-scan -> scatter (perm).
//   Main: 1 block = 16 consecutive sorted elems; 4 waves split d (32 rows
//   each, W slice in 64 VGPRs, reloaded only on relation change). Score is
//   separable per d-chunk -> per-wave partial, one final LDS combine.

#define RANK 128
#define M 16            // batch elems per block in main kernel

// ---------------- aux: sort-by-relation infrastructure ----------------

__global__ void zero_k(int* p, int n) {
  int i = blockIdx.x * blockDim.x + threadIdx.x;
  if (i < n) p[i] = 0;
}

__global__ void hist_k(const int* __restrict__ rels, int n, int* __restrict__ hist) {
  int i = blockIdx.x * blockDim.x + threadIdx.x;
  if (i < n) atomicAdd(&hist[rels[i]], 1);
}

__global__ __launch_bounds__(1024) void scan_k(const int* __restrict__ hist,
                                               int* __restrict__ cursor, int nrel) {
  __shared__ int sdata[1024];
  int t = threadIdx.x;
  int own = (t < nrel) ? hist[t] : 0;
  sdata[t] = own;
  __syncthreads();
  for (int off = 1; off < 1024; off <<= 1) {
    int v = (t >= off) ? sdata[t - off] : 0;
    __syncthreads();
    sdata[t] += v;
    __syncthreads();
  }
  if (t < nrel) cursor[t] = sdata[t] - own;   // exclusive prefix
}

__global__ void scatter_k(const int* __restrict__ rels, int n,
                          int* __restrict__ cursor, int* __restrict__ perm,
                          int* __restrict__ rsorted) {
  int i = blockIdx.x * blockDim.x + threadIdx.x;
  if (i < n) {
    int r = rels[i];
    int pos = atomicAdd(&cursor[r], 1);
    perm[pos] = i;
    rsorted[pos] = r;
  }
}

// ---------------- main scoring kernel ----------------

__global__ __launch_bounds__(256) void rescal_main(
    const float* __restrict__ E, const float* __restrict__ W,
    const int* __restrict__ heads, const int* __restrict__ tails,
    const int* __restrict__ perm, const int* __restrict__ rsorted,
    float* __restrict__ out, int batch)
{
  const int nwg = gridDim.x;
  // Bijective XCD-aware swizzle: each XCD gets a contiguous sorted range.
  const int q = nwg / 8, r8 = nwg % 8;
  const int xcd = blockIdx.x % 8, sub = blockIdx.x / 8;
  const int swz = (xcd < r8) ? xcd * (q + 1) + sub
                             : r8 * (q + 1) + (xcd - r8) * q + sub;
  const int base = swz * M;

  const int wib  = threadIdx.x >> 6;   // wave 0..3 owns d-rows [32*wib, 32*wib+32)
  const int lane = threadIdx.x & 63;   // lane owns output cols {2*lane, 2*lane+1}

  __shared__ float ehs[4][32];         // per-wave e_h slice (no cross-wave use)
  __shared__ float part[4][M];

  float2 wreg[32];                     // this wave's W_r slice: 32 rows x 2 cols
  int rcur = -1;
  float s[M];

  #pragma unroll
  for (int e = 0; e < M; ++e) {
    const int gi  = base + e;
    const bool v  = (gi < batch);
    const int gic = v ? gi : (batch - 1);
    const int b   = perm[gic];
    const int r   = rsorted[gic];

    if (r != rcur) {                   // block-uniform branch (sorted order)
      rcur = r;
      const float2* W2 = (const float2*)(W + (size_t)r * RANK * RANK);
      #pragma unroll
      for (int d = 0; d < 32; ++d)
        wreg[d] = W2[(wib * 32 + d) * 64 + lane];  // coalesced 512B/row
    }

    const int h = heads[b];
    const int t = tails[b];

    // Stage this wave's 32-value e_h slice (wave-internal LDS dependency;
    // per-wave buffer so no __syncthreads needed).
    if (lane < 32) ehs[wib][lane] = E[(size_t)h * RANK + wib * 32 + lane];

    float mx = 0.f, my = 0.f;
    #pragma unroll
    for (int d = 0; d < 32; ++d) {
      const float x = ehs[wib][d];     // LDS broadcast
      mx = fmaf(x, wreg[d].x, mx);
      my = fmaf(x, wreg[d].y, my);
    }

    const float2 et = ((const float2*)(E + (size_t)t * RANK))[lane];
    float sv = fmaf(mx, et.x, my * et.y);
    #pragma unroll
    for (int off = 32; off; off >>= 1)
      sv += __shfl_down(sv, off, 64);
    s[e] = sv;                         // lane 0 holds the wave partial
  }

  if (lane == 0) {
    #pragma unroll
    for (int e = 0; e < M; ++e) part[wib][e] = s[e];
  }
  __syncthreads();

  if (threadIdx.x < M) {
    const int gi = base + threadIdx.x;
    if (gi < batch) {
      const float tot = part[0][threadIdx.x] + part[1][threadIdx.x]
                      + part[2][threadIdx.x] + part[3][threadIdx.x];
      out[perm[gi]] = tot;
    }
  }
}

// ---------------- launch ----------------

extern "C" void kernel_launch(void* const* d_in, const int* in_sizes, int n_in,
                              void* d_out, int out_size, void* d_ws, size_t ws_size,
                              hipStream_t stream)
{
  const float* E     = (const float*)d_in[0];
  const float* W     = (const float*)d_in[1];
  const int*   heads = (const int*)d_in[2];
  const int*   rels  = (const int*)d_in[3];
  const int*   tails = (const int*)d_in[4];
  float* out = (float*)d_out;

  const int batch = in_sizes[2];                       // 16384
  const int nrel  = in_sizes[1] / (RANK * RANK);       // 1000 (<=1024 assumed)

  int* ws      = (int*)d_ws;
  int* hist    = ws;                  // [<=1024]
  int* cursor  = ws + 1024;           // [<=1024]
  int* perm    = ws + 2048;           // [batch]
  int* rsorted = perm + batch;        // [batch]

  zero_k<<<(nrel + 255) / 256, 256, 0, stream>>>(hist, nrel);
  hist_k<<<(batch + 255) / 256, 256, 0, stream>>>(rels, batch, hist);
  scan_k<<<1, 1024, 0, stream>>>(hist, cursor, nrel);
  scatter_k<<<(batch + 255) / 256, 256, 0, stream>>>(rels, batch, cursor, perm, rsorted);

  const int nblk = (batch + M - 1) / M;                // 1024
  rescal_main<<<nblk, 256, 0, stream>>>(E, W, heads, tails, perm, rsorted, out, batch);
}